// Round 3
// baseline (699.883 us; speedup 1.0000x reference)
//
#include <hip/hip_runtime.h>
#include <hip/hip_bf16.h>

#define N_VOX 200000
#define KOFF 27
#define PPK 100000
#define C 64
#define BN_EPS 1e-5f

typedef __bf16 bf16x8 __attribute__((ext_vector_type(8)));
typedef __bf16 bf16x4 __attribute__((ext_vector_type(4)));
typedef float f32x4 __attribute__((ext_vector_type(4)));

// ---------------------------------------------------------------------------
// features fp32 -> bf16 (RNE), vectorized: 1 float4 in -> 4 bf16 (8B) out.
// ---------------------------------------------------------------------------
__global__ __launch_bounds__(256)
void convert_features(const float* __restrict__ f, __bf16* __restrict__ fb)
{
    const size_t total4 = (size_t)N_VOX * C / 4;
    const size_t i = (size_t)blockIdx.x * blockDim.x + threadIdx.x;
    if (i >= total4) return;
    const float4 v = ((const float4*)f)[i];
    bf16x4 o;
    o.x = (__bf16)v.x; o.y = (__bf16)v.y; o.z = (__bf16)v.z; o.w = (__bf16)v.w;
    ((bf16x4*)fb)[i] = o;
}

// ---------------------------------------------------------------------------
// weight [k][cin][cout] fp32 -> wt [k][cout][cin] bf16 (transposed).
// ---------------------------------------------------------------------------
__global__ __launch_bounds__(256)
void convert_weight(const float* __restrict__ w, __bf16* __restrict__ wt)
{
    const int k = blockIdx.x;
    const float* W = w + (size_t)k * C * C;
    __bf16* Wt = wt + (size_t)k * C * C;
    for (int idx = threadIdx.x; idx < C * C; idx += 256) {
        const int ci = idx >> 6, co = idx & 63;
        Wt[co * C + ci] = (__bf16)W[idx];
    }
}

// ===========================================================================
// Rulebook inversion (per k-chunk): histogram -> exclusive scan.
// Rank assignment is fused into conv_scatter (cursor atomics).
// ===========================================================================
__global__ __launch_bounds__(256)
void hist_kernel(const int* __restrict__ out_idx, unsigned* __restrict__ counts,
                 int k0, int npair)
{
    const int i = blockIdx.x * 256 + threadIdx.x;
    if (i < npair) {
        const int o = out_idx[(size_t)k0 * PPK + i];
        atomicAdd(&counts[o], 1u);
    }
}

// exclusive scan of counts[200000] -> offsets; also RE-ZEROES counts so the
// next chunk's hist needs no memset. 1024 elems/block, 196 blocks.
__global__ __launch_bounds__(256)
void scan1(unsigned* __restrict__ counts, unsigned* __restrict__ offsets,
           unsigned* __restrict__ bsums)
{
    __shared__ unsigned sdata[256];
    const int t = threadIdx.x;
    const int base = blockIdx.x * 1024 + t * 4;
    unsigned v[4]; unsigned s = 0;
#pragma unroll
    for (int u = 0; u < 4; ++u) {
        const bool ok = (base + u < N_VOX);
        v[u] = ok ? counts[base + u] : 0u;
        if (ok) counts[base + u] = 0u;
        s += v[u];
    }
    sdata[t] = s;
    __syncthreads();
    for (int off = 1; off < 256; off <<= 1) {
        const unsigned add = (t >= off) ? sdata[t - off] : 0u;
        __syncthreads();
        sdata[t] += add;
        __syncthreads();
    }
    const unsigned incl = sdata[t];
    unsigned run = incl - s;          // exclusive prefix for this thread
    if (t == 255) bsums[blockIdx.x] = incl;
#pragma unroll
    for (int u = 0; u < 4; ++u) {
        if (base + u < N_VOX) offsets[base + u] = run;
        run += v[u];
    }
}

__global__ __launch_bounds__(256)
void scan2(unsigned* __restrict__ bsums, int nb)
{
    __shared__ unsigned sdata[256];
    const int t = threadIdx.x;
    const unsigned s = (t < nb) ? bsums[t] : 0u;
    sdata[t] = s;
    __syncthreads();
    for (int off = 1; off < 256; off <<= 1) {
        const unsigned add = (t >= off) ? sdata[t - off] : 0u;
        __syncthreads();
        sdata[t] += add;
        __syncthreads();
    }
    if (t < nb) bsums[t] = sdata[t] - s;   // exclusive
}

__global__ __launch_bounds__(256)
void scan3(unsigned* __restrict__ offsets, const unsigned* __restrict__ bsums,
           unsigned* __restrict__ cursor)
{
    const int i = blockIdx.x * 256 + threadIdx.x;
    if (i < N_VOX) {
        const unsigned v = offsets[i] + bsums[i >> 10];
        offsets[i] = v;
        cursor[i] = v;
    }
}

// ===========================================================================
// Conv via MFMA, scatter partial rows (bf16) to out-sorted slots, NO f32
// atomics. Slot = atomicAdd(cursor[out]) inline; distributed via wave shfl.
// LDS: 32 KB XOR-swizzled A-tile (chunk ^= row&7) -> 5 blocks/CU, 0 bank
// conflicts (verified round 2).
// Stores are NORMAL (write-back): with chunk capped at 9 k-offsets the
// partial buffer (115 MB) + featb (25.6) + out (51.2) fit the 256 MB
// memory-side L3, so partial writes/reads are absorbed there. Round-2
// non-temporal stores forced HBM write-through (WRITE 175->219 MB, +25 us):
// reverted.
// Partial row layout c' = m16*4 + nt (true channel c = nt*16 + m16).
// ===========================================================================
__global__ __launch_bounds__(256)
void conv_scatter(const __bf16* __restrict__ featb, const __bf16* __restrict__ wtb,
                  const int* __restrict__ in_idx, const int* __restrict__ out_idx,
                  unsigned* __restrict__ cursor, __bf16* __restrict__ partial,
                  int k0)
{
    constexpr int TP = 256;       // pairs per tile
    __shared__ __bf16 sA[TP * 64];   // 32 KB exactly

    const int k = k0 + blockIdx.y;
    const int tile_base = blockIdx.x * TP;
    const int t = threadIdx.x;
    const int lane = t & 63;
    const int wave = t >> 6;
    const int m16 = lane & 15;    // A: pair-row in 16; B: cout; C/D: col
    const int quad = lane >> 4;   // 0..3

    // B fragments from Wt[k][cout][cin]
    const __bf16* Wt = wtb + (size_t)k * C * C;
    bf16x8 bfrag[4][2];
#pragma unroll
    for (int nt = 0; nt < 4; ++nt)
#pragma unroll
        for (int kc = 0; kc < 2; ++kc)
            bfrag[nt][kc] = *(const bf16x8*)(Wt + (nt * 16 + m16) * C + kc * 32 + quad * 8);

    // rank of this thread's pair (slot within its out-voxel's range)
    unsigned my_rank = 0u;
    {
        const int pair = tile_base + t;
        if (pair < PPK) {
            const int o = out_idx[(size_t)k * PPK + pair];
            my_rank = atomicAdd(&cursor[o], 1u);
        }
    }

    // stage gathered A rows: thread t loads row (t>>3)+32*it, 16B chunk (t&7),
    // stored at swizzled chunk (c8 ^ (r&7)).
    const int c8 = t & 7;
    const int r0 = t >> 3;
#pragma unroll
    for (int it = 0; it < 8; ++it) {
        const int r = r0 + it * 32;               // r&7 == r0&7
        const int pair = tile_base + r;
        const int row = (pair < PPK) ? in_idx[(size_t)k * PPK + pair] : 0;
        const float4 v = *(const float4*)(featb + (size_t)row * C + c8 * 8);
        *(float4*)(sA + r * 64 + ((c8 ^ (r0 & 7)) << 3)) = v;
    }
    __syncthreads();

    // MFMA: wave owns pairs [wave*64, wave*64+64). Read chunk (kc*4+quad)^(m16&7).
    f32x4 acc[4][4] = {};
    const int mbase = wave * 64;
#pragma unroll
    for (int kc = 0; kc < 2; ++kc) {
        bf16x8 afrag[4];
#pragma unroll
        for (int mt = 0; mt < 4; ++mt)
            afrag[mt] = *(const bf16x8*)(sA + (mbase + mt * 16 + m16) * 64
                                         + ((((kc << 2) | quad) ^ (m16 & 7)) << 3));
#pragma unroll
        for (int nt = 0; nt < 4; ++nt)
#pragma unroll
            for (int mt = 0; mt < 4; ++mt)
                acc[mt][nt] = __builtin_amdgcn_mfma_f32_16x16x32_bf16(
                    afrag[mt], bfrag[nt][kc], acc[mt][nt], 0, 0, 0);
    }

    // scatter partial rows: per (mt,reg) row, 16 lanes of a quad write the
    // full 128B bf16 row (8B per lane) at its out-sorted slot.
#pragma unroll
    for (int mt = 0; mt < 4; ++mt) {
#pragma unroll
        for (int reg = 0; reg < 4; ++reg) {
            const int rloc = mt * 16 + quad * 4 + reg;       // row within wave stripe
            const unsigned slot = __shfl(my_rank, rloc, 64);
            const int pair = tile_base + mbase + rloc;
            if (pair < PPK) {
                bf16x4 pv;
                pv.x = (__bf16)acc[mt][0][reg];
                pv.y = (__bf16)acc[mt][1][reg];
                pv.z = (__bf16)acc[mt][2][reg];
                pv.w = (__bf16)acc[mt][3][reg];
                *(bf16x4*)(partial + (size_t)slot * C + (m16 << 2)) = pv;
            }
        }
    }
}

// ---------------------------------------------------------------------------
// Reduce: one out row per WAVE (no intra-wave divergence over Poisson counts).
// Lanes: e = lane>>4 processes slot beg+e (4 slots/iter, 512B coalesced),
// j = lane&15 covers permuted c' = 4j..4j+3 -> channels {j,16+j,32+j,48+j}.
// Cross-e sum via shfl_xor(16,32). Plain loads (partial is L3-resident;
// round-2 NT loads forced HBM streams: reverted).
// ---------------------------------------------------------------------------
__global__ __launch_bounds__(256)
void reduce_kernel(const __bf16* __restrict__ partial,
                   const unsigned* __restrict__ offsets,
                   float* __restrict__ out, const int first, const unsigned np)
{
    const int wave = threadIdx.x >> 6;
    const int lane = threadIdx.x & 63;
    const int e = lane >> 4;
    const int j = lane & 15;
    const int o = blockIdx.x * 4 + wave;
    if (o >= N_VOX) return;
    const unsigned beg = offsets[o];
    const unsigned end = (o + 1 < N_VOX) ? offsets[o + 1] : np;
    float a0 = 0.f, a1 = 0.f, a2 = 0.f, a3 = 0.f;
    for (unsigned s = beg + e; s < end; s += 4) {
        const bf16x4 v = *(const bf16x4*)(partial + (size_t)s * C + (j << 2));
        a0 += (float)v.x; a1 += (float)v.y; a2 += (float)v.z; a3 += (float)v.w;
    }
#pragma unroll
    for (int mask = 16; mask <= 32; mask <<= 1) {
        a0 += __shfl_xor(a0, mask, 64);
        a1 += __shfl_xor(a1, mask, 64);
        a2 += __shfl_xor(a2, mask, 64);
        a3 += __shfl_xor(a3, mask, 64);
    }
    if (e == 0) {
        float* orow = out + (size_t)o * C;
        if (first) {
            orow[j] = a0; orow[16 + j] = a1; orow[32 + j] = a2; orow[48 + j] = a3;
        } else {
            orow[j] += a0; orow[16 + j] += a1; orow[32 + j] += a2; orow[48 + j] += a3;
        }
    }
}

// ===========================================================================
// Fallback conv (proven): atomic scatter-add. Used only if workspace is too
// small for the sorted-partial path.
// ===========================================================================
__global__ __launch_bounds__(256)
void conv_mfma(const __bf16* __restrict__ featb, const __bf16* __restrict__ wtb,
               const int* __restrict__ in_idx, const int* __restrict__ out_idx,
               float* __restrict__ out)
{
    constexpr int TP = 256;
    constexpr int STRIDE = 72;
    __shared__ __bf16 sA[TP * STRIDE];
    __shared__ int s_out[TP];

    const int k = blockIdx.y;
    const int tile_base = blockIdx.x * TP;
    const int t = threadIdx.x;
    const int lane = t & 63;
    const int wave = t >> 6;
    const int m16 = lane & 15;
    const int quad = lane >> 4;

    const __bf16* Wt = wtb + (size_t)k * C * C;
    bf16x8 bfrag[4][2];
#pragma unroll
    for (int nt = 0; nt < 4; ++nt)
#pragma unroll
        for (int kc = 0; kc < 2; ++kc)
            bfrag[nt][kc] = *(const bf16x8*)(Wt + (nt * 16 + m16) * C + kc * 32 + quad * 8);

    {
        const int pair = tile_base + t;
        s_out[t] = (pair < PPK) ? out_idx[(size_t)k * PPK + pair] : 0;
    }

    const int c8 = t & 7;
    const int r0 = t >> 3;
#pragma unroll
    for (int it = 0; it < 8; ++it) {
        const int r = r0 + it * 32;
        const int pair = tile_base + r;
        const int row = (pair < PPK) ? in_idx[(size_t)k * PPK + pair] : 0;
        const float4 v = *(const float4*)(featb + (size_t)row * C + c8 * 8);
        *(float4*)(sA + r * STRIDE + c8 * 8) = v;
    }
    __syncthreads();

    f32x4 acc[4][4] = {};
    const int mbase = wave * 64;
#pragma unroll
    for (int kc = 0; kc < 2; ++kc) {
        bf16x8 afrag[4];
#pragma unroll
        for (int mt = 0; mt < 4; ++mt)
            afrag[mt] = *(const bf16x8*)(sA + (mbase + mt * 16 + m16) * STRIDE + kc * 32 + quad * 8);
#pragma unroll
        for (int nt = 0; nt < 4; ++nt)
#pragma unroll
            for (int mt = 0; mt < 4; ++mt)
                acc[mt][nt] = __builtin_amdgcn_mfma_f32_16x16x32_bf16(
                    afrag[mt], bfrag[nt][kc], acc[mt][nt], 0, 0, 0);
    }

#pragma unroll
    for (int mt = 0; mt < 4; ++mt) {
#pragma unroll
        for (int reg = 0; reg < 4; ++reg) {
            const int r = mbase + mt * 16 + quad * 4 + reg;
            const int pair = tile_base + r;
            if (pair < PPK) {
                const int o = s_out[r];
                float* orow = out + (size_t)o * C + m16;
#pragma unroll
                for (int nt = 0; nt < 4; ++nt)
                    unsafeAtomicAdd(orow + nt * 16, acc[mt][nt][reg]);
            }
        }
    }
}

// ---------------------------------------------------------------------------
// Per-channel sum / sum-of-squares (bias skipped: cancels under BN).
// ---------------------------------------------------------------------------
__global__ __launch_bounds__(256)
void stats_kernel(const float* __restrict__ out,
                  float* __restrict__ stats,
                  int rows_per_block)
{
    __shared__ float ssum[256];
    __shared__ float ssq[256];
    const int c   = threadIdx.x & 63;
    const int sub = threadIdx.x >> 6;
    const int row0 = blockIdx.x * rows_per_block;
    const int row1 = min(row0 + rows_per_block, N_VOX);
    float s = 0.f, q = 0.f;
    for (int r = row0 + sub; r < row1; r += 4) {
        const float v = out[(size_t)r * C + c];
        s += v;
        q += v * v;
    }
    ssum[threadIdx.x] = s;
    ssq[threadIdx.x]  = q;
    __syncthreads();
    if (sub == 0) {
        s = ssum[c] + ssum[64 + c] + ssum[128 + c] + ssum[192 + c];
        q = ssq[c]  + ssq[64 + c]  + ssq[128 + c]  + ssq[192 + c];
        unsafeAtomicAdd(&stats[c], s);
        unsafeAtomicAdd(&stats[64 + c], q);
    }
}

__global__ void finalize_params(const float* __restrict__ stats,
                                const float* __restrict__ gamma,
                                const float* __restrict__ beta,
                                float* __restrict__ ss)
{
    const int c = threadIdx.x;
    const float inv_n = 1.0f / (float)N_VOX;
    const float mean  = stats[c] * inv_n;
    const float var   = stats[64 + c] * inv_n - mean * mean;
    const float scale = rsqrtf(var + BN_EPS) * gamma[c];
    ss[c]      = scale;
    ss[64 + c] = beta[c] - mean * scale;
}

__global__ __launch_bounds__(256)
void norm_kernel(float* __restrict__ out, const float* __restrict__ ss)
{
    const size_t total4 = (size_t)N_VOX * C / 4;
    const size_t idx = (size_t)blockIdx.x * blockDim.x + threadIdx.x;
    if (idx >= total4) return;
    const int c4 = (int)(idx & 15);
    float4 v = ((const float4*)out)[idx];
    const float4 sc = ((const float4*)ss)[c4];
    const float4 sh = ((const float4*)(ss + 64))[c4];
    v.x = fmaxf(v.x * sc.x + sh.x, 0.f);
    v.y = fmaxf(v.y * sc.y + sh.y, 0.f);
    v.z = fmaxf(v.z * sc.z + sh.z, 0.f);
    v.w = fmaxf(v.w * sc.w + sh.w, 0.f);
    ((float4*)out)[idx] = v;
}

static inline size_t align_up(size_t x) { return (x + 255) & ~(size_t)255; }

extern "C" void kernel_launch(void* const* d_in, const int* in_sizes, int n_in,
                              void* d_out, int out_size, void* d_ws, size_t ws_size,
                              hipStream_t stream)
{
    const float* features = (const float*)d_in[0];
    const float* weight   = (const float*)d_in[1];
    // d_in[2] = bias: cancels under BN, unused.
    const float* gamma    = (const float*)d_in[3];
    const float* beta     = (const float*)d_in[4];
    const int*   in_idx   = (const int*)d_in[5];
    const int*   out_idx  = (const int*)d_in[6];
    float* out = (float*)d_out;

    // workspace layout
    char* base = (char*)d_ws;
    size_t off = 0;
    __bf16* featb = (__bf16*)(base + off); off += align_up((size_t)N_VOX * C * 2);
    __bf16* wtb   = (__bf16*)(base + off); off += align_up((size_t)KOFF * C * C * 2);
    float*  stats = (float*)(base + off);  off += align_up(128 * 4);
    float*  ss    = (float*)(base + off);  off += align_up(128 * 4);
    unsigned* counts  = (unsigned*)(base + off); off += align_up((size_t)N_VOX * 4);
    unsigned* offsets = (unsigned*)(base + off); off += align_up((size_t)N_VOX * 4);
    unsigned* cursor  = (unsigned*)(base + off); off += align_up((size_t)N_VOX * 4);
    unsigned* bsums   = (unsigned*)(base + off); off += align_up(256 * 4);
    const size_t fixed = off;

    // per k-offset per chunk: partial bf16[PPK][64] = 128 B/pair.
    // CAP at 9 offsets (115 MB): partial + featb (25.6) + out (51.2) must fit
    // the 256 MB memory-side L3 so the partial round-trip never touches HBM.
    int g_cap = 0;
    if (ws_size > fixed)
        g_cap = (int)((ws_size - fixed) / ((size_t)PPK * 128));
    if (g_cap > 9) g_cap = 9;

    hipMemsetAsync(stats, 0, 128 * sizeof(float), stream);

    const size_t total4 = (size_t)N_VOX * C / 4;
    convert_features<<<(int)((total4 + 255) / 256), 256, 0, stream>>>(features, featb);
    convert_weight<<<KOFF, 256, 0, stream>>>(weight, wtb);

    if (g_cap >= 2) {
        // sorted-partial path: invert rulebook per chunk, no f32 atomics.
        const int G = (KOFF + g_cap - 1) / g_cap;
        __bf16* partial = (__bf16*)(base + off);
        const int gbase_sz = KOFF / G, rem = KOFF % G;
        // counts must be zero before the first hist; scan1 re-zeroes each chunk.
        hipMemsetAsync(counts, 0, (size_t)N_VOX * 4, stream);
        int k0 = 0;
        for (int ci = 0; ci < G; ++ci) {
            const int g = gbase_sz + (ci < rem ? 1 : 0);
            const int np = g * PPK;
            hist_kernel<<<(np + 255) / 256, 256, 0, stream>>>(out_idx, counts, k0, np);
            scan1<<<(N_VOX + 1023) / 1024, 256, 0, stream>>>(counts, offsets, bsums);
            scan2<<<1, 256, 0, stream>>>(bsums, (N_VOX + 1023) / 1024);
            scan3<<<(N_VOX + 255) / 256, 256, 0, stream>>>(offsets, bsums, cursor);
            dim3 cgrid((PPK + 255) / 256, g);
            conv_scatter<<<cgrid, 256, 0, stream>>>(featb, wtb, in_idx, out_idx,
                                                    cursor, partial, k0);
            reduce_kernel<<<(N_VOX + 3) / 4, 256, 0, stream>>>(partial, offsets, out,
                                                               ci == 0 ? 1 : 0,
                                                               (unsigned)np);
            k0 += g;
        }
    } else {
        // fallback: proven atomic path
        hipMemsetAsync(out, 0, (size_t)N_VOX * C * sizeof(float), stream);
        dim3 cgrid((PPK + 255) / 256, KOFF);
        conv_mfma<<<cgrid, 256, 0, stream>>>(featb, wtb, in_idx, out_idx, out);
    }

    const int rpb = (N_VOX + 511) / 512;
    stats_kernel<<<512, 256, 0, stream>>>(out, stats, rpb);

    finalize_params<<<1, 64, 0, stream>>>(stats, gamma, beta, ss);

    norm_kernel<<<(int)((total4 + 255) / 256), 256, 0, stream>>>(out, ss);
}

// Round 4
// 660.642 us; speedup vs baseline: 1.0594x; 1.0594x over previous
//
#include <hip/hip_runtime.h>
#include <hip/hip_bf16.h>

#define N_VOX 200000
#define KOFF 27
#define PPK 100000
#define C 64
#define BN_EPS 1e-5f

typedef __bf16 bf16x8 __attribute__((ext_vector_type(8)));
typedef __bf16 bf16x4 __attribute__((ext_vector_type(4)));
typedef float f32x4 __attribute__((ext_vector_type(4)));

// ---------------------------------------------------------------------------
// features fp32 -> bf16 (RNE), vectorized: 1 float4 in -> 4 bf16 (8B) out.
// ---------------------------------------------------------------------------
__global__ __launch_bounds__(256)
void convert_features(const float* __restrict__ f, __bf16* __restrict__ fb)
{
    const size_t total4 = (size_t)N_VOX * C / 4;
    const size_t i = (size_t)blockIdx.x * blockDim.x + threadIdx.x;
    if (i >= total4) return;
    const float4 v = ((const float4*)f)[i];
    bf16x4 o;
    o.x = (__bf16)v.x; o.y = (__bf16)v.y; o.z = (__bf16)v.z; o.w = (__bf16)v.w;
    ((bf16x4*)fb)[i] = o;
}

// ---------------------------------------------------------------------------
// weight [k][cin][cout] fp32 -> wt [k][cout][cin] bf16 (transposed).
// ---------------------------------------------------------------------------
__global__ __launch_bounds__(256)
void convert_weight(const float* __restrict__ w, __bf16* __restrict__ wt)
{
    const int k = blockIdx.x;
    const float* W = w + (size_t)k * C * C;
    __bf16* Wt = wt + (size_t)k * C * C;
    for (int idx = threadIdx.x; idx < C * C; idx += 256) {
        const int ci = idx >> 6, co = idx & 63;
        Wt[co * C + ci] = (__bf16)W[idx];
    }
}

// ===========================================================================
// Rulebook inversion (per k-chunk): histogram (capturing per-pair rank) ->
// exclusive scan -> slot = offsets[o] + rank (in-place on the rank buffer).
// All atomics live HERE (latency-tolerant streaming passes), NOT in conv:
// round 2/3 fused the cursor atomic into conv's scatter-address chain and
// lost 2.2 us/offset (9.4 vs round-1's 7.2).
// ===========================================================================
__global__ __launch_bounds__(256)
void hist_kernel(const int* __restrict__ out_idx, unsigned* __restrict__ counts,
                 unsigned* __restrict__ slot, int k0, int npair)
{
    const int i = blockIdx.x * 256 + threadIdx.x;
    if (i < npair) {
        const int o = out_idx[(size_t)k0 * PPK + i];
        slot[i] = atomicAdd(&counts[o], 1u);   // rank within voxel (this chunk)
    }
}

// exclusive scan of counts[200000] -> offsets; also RE-ZEROES counts so the
// next chunk's hist needs no memset. 1024 elems/block, 196 blocks.
__global__ __launch_bounds__(256)
void scan1(unsigned* __restrict__ counts, unsigned* __restrict__ offsets,
           unsigned* __restrict__ bsums)
{
    __shared__ unsigned sdata[256];
    const int t = threadIdx.x;
    const int base = blockIdx.x * 1024 + t * 4;
    unsigned v[4]; unsigned s = 0;
#pragma unroll
    for (int u = 0; u < 4; ++u) {
        const bool ok = (base + u < N_VOX);
        v[u] = ok ? counts[base + u] : 0u;
        if (ok) counts[base + u] = 0u;
        s += v[u];
    }
    sdata[t] = s;
    __syncthreads();
    for (int off = 1; off < 256; off <<= 1) {
        const unsigned add = (t >= off) ? sdata[t - off] : 0u;
        __syncthreads();
        sdata[t] += add;
        __syncthreads();
    }
    const unsigned incl = sdata[t];
    unsigned run = incl - s;          // exclusive prefix for this thread
    if (t == 255) bsums[blockIdx.x] = incl;
#pragma unroll
    for (int u = 0; u < 4; ++u) {
        if (base + u < N_VOX) offsets[base + u] = run;
        run += v[u];
    }
}

__global__ __launch_bounds__(256)
void scan2(unsigned* __restrict__ bsums, int nb)
{
    __shared__ unsigned sdata[256];
    const int t = threadIdx.x;
    const unsigned s = (t < nb) ? bsums[t] : 0u;
    sdata[t] = s;
    __syncthreads();
    for (int off = 1; off < 256; off <<= 1) {
        const unsigned add = (t >= off) ? sdata[t - off] : 0u;
        __syncthreads();
        sdata[t] += add;
        __syncthreads();
    }
    if (t < nb) bsums[t] = sdata[t] - s;   // exclusive
}

__global__ __launch_bounds__(256)
void scan3(unsigned* __restrict__ offsets, const unsigned* __restrict__ bsums)
{
    const int i = blockIdx.x * 256 + threadIdx.x;
    if (i < N_VOX) offsets[i] += bsums[i >> 10];
}

// slot[i] = offsets[out] + rank  (in-place; offsets gather is L2-resident 800KB)
__global__ __launch_bounds__(256)
void slot_fill(const int* __restrict__ out_idx,
               const unsigned* __restrict__ offsets,
               unsigned* __restrict__ slot, int k0, int npair)
{
    const int i = blockIdx.x * 256 + threadIdx.x;
    if (i < npair) {
        const int o = out_idx[(size_t)k0 * PPK + i];
        slot[i] += offsets[o];
    }
}

// ===========================================================================
// Conv via MFMA, scatter partial rows (bf16) to out-sorted slots. NO atomics
// anywhere in this kernel: slot[] is precomputed, read coalesced (one u32 per
// thread), distributed to store lanes via wave shfl.
// LDS: 32 KB XOR-swizzled A-tile (chunk ^= row&7) -> 5 blocks/CU, 0 bank
// conflicts (verified round 2). Plain write-back stores (NT hurt, round 2).
// Partial row layout c' = m16*4 + nt (true channel c = nt*16 + m16).
// ===========================================================================
__global__ __launch_bounds__(256)
void conv_scatter(const __bf16* __restrict__ featb, const __bf16* __restrict__ wtb,
                  const int* __restrict__ in_idx, const unsigned* __restrict__ slot,
                  __bf16* __restrict__ partial, int k0)
{
    constexpr int TP = 256;       // pairs per tile
    __shared__ __bf16 sA[TP * 64];   // 32 KB exactly

    const int kloc = blockIdx.y;
    const int k = k0 + kloc;
    const int tile_base = blockIdx.x * TP;
    const int t = threadIdx.x;
    const int lane = t & 63;
    const int wave = t >> 6;
    const int m16 = lane & 15;    // A: pair-row in 16; B: cout; C/D: col
    const int quad = lane >> 4;   // 0..3

    // this thread's pair slot (coalesced read; consumed via shfl at the end)
    unsigned my_slot = 0u;
    {
        const int pair = tile_base + t;
        if (pair < PPK) my_slot = slot[(size_t)kloc * PPK + pair];
    }

    // B fragments from Wt[k][cout][cin]
    const __bf16* Wt = wtb + (size_t)k * C * C;
    bf16x8 bfrag[4][2];
#pragma unroll
    for (int nt = 0; nt < 4; ++nt)
#pragma unroll
        for (int kc = 0; kc < 2; ++kc)
            bfrag[nt][kc] = *(const bf16x8*)(Wt + (nt * 16 + m16) * C + kc * 32 + quad * 8);

    // stage gathered A rows: thread t loads row (t>>3)+32*it, 16B chunk (t&7),
    // stored at swizzled chunk (c8 ^ (r&7)).
    const int c8 = t & 7;
    const int r0 = t >> 3;
#pragma unroll
    for (int it = 0; it < 8; ++it) {
        const int r = r0 + it * 32;               // r&7 == r0&7
        const int pair = tile_base + r;
        const int row = (pair < PPK) ? in_idx[(size_t)k * PPK + pair] : 0;
        const float4 v = *(const float4*)(featb + (size_t)row * C + c8 * 8);
        *(float4*)(sA + r * 64 + ((c8 ^ (r0 & 7)) << 3)) = v;
    }
    __syncthreads();

    // MFMA: wave owns pairs [wave*64, wave*64+64). Read chunk (kc*4+quad)^(m16&7).
    f32x4 acc[4][4] = {};
    const int mbase = wave * 64;
#pragma unroll
    for (int kc = 0; kc < 2; ++kc) {
        bf16x8 afrag[4];
#pragma unroll
        for (int mt = 0; mt < 4; ++mt)
            afrag[mt] = *(const bf16x8*)(sA + (mbase + mt * 16 + m16) * 64
                                         + ((((kc << 2) | quad) ^ (m16 & 7)) << 3));
#pragma unroll
        for (int nt = 0; nt < 4; ++nt)
#pragma unroll
            for (int mt = 0; mt < 4; ++mt)
                acc[mt][nt] = __builtin_amdgcn_mfma_f32_16x16x32_bf16(
                    afrag[mt], bfrag[nt][kc], acc[mt][nt], 0, 0, 0);
    }

    // scatter partial rows: per (mt,reg) row, 16 lanes of a quad write the
    // full 128B bf16 row (8B per lane) at its out-sorted slot.
#pragma unroll
    for (int mt = 0; mt < 4; ++mt) {
#pragma unroll
        for (int reg = 0; reg < 4; ++reg) {
            const int rloc = mt * 16 + quad * 4 + reg;       // row within wave stripe
            const unsigned s = __shfl(my_slot, rloc, 64);
            const int pair = tile_base + mbase + rloc;
            if (pair < PPK) {
                bf16x4 pv;
                pv.x = (__bf16)acc[mt][0][reg];
                pv.y = (__bf16)acc[mt][1][reg];
                pv.z = (__bf16)acc[mt][2][reg];
                pv.w = (__bf16)acc[mt][3][reg];
                *(bf16x4*)(partial + (size_t)s * C + (m16 << 2)) = pv;
            }
        }
    }
}

// ---------------------------------------------------------------------------
// Reduce: one out row per WAVE, GRID-STRIDE over voxels (1024 blocks instead
// of 50K tiny blocks: round-3's per-block dispatch overhead eliminated).
// Lanes: e = lane>>4 processes slots beg+e, beg+e+4, ... (512B/iter
// coalesced); j = lane&15 covers permuted c' = 4j..4j+3 -> channels
// {j,16+j,32+j,48+j}. Cross-e sum via shfl_xor(16,32).
// ---------------------------------------------------------------------------
__global__ __launch_bounds__(256)
void reduce_kernel(const __bf16* __restrict__ partial,
                   const unsigned* __restrict__ offsets,
                   float* __restrict__ out, const int first, const unsigned np)
{
    const int wave = threadIdx.x >> 6;
    const int lane = threadIdx.x & 63;
    const int e = lane >> 4;
    const int j = lane & 15;
    const int stride = gridDim.x * 4;
    for (int o = blockIdx.x * 4 + wave; o < N_VOX; o += stride) {
        const unsigned beg = offsets[o];
        const unsigned end = (o + 1 < N_VOX) ? offsets[o + 1] : np;
        float a0 = 0.f, a1 = 0.f, a2 = 0.f, a3 = 0.f;
        for (unsigned s = beg + e; s < end; s += 4) {
            const bf16x4 v = *(const bf16x4*)(partial + (size_t)s * C + (j << 2));
            a0 += (float)v.x; a1 += (float)v.y; a2 += (float)v.z; a3 += (float)v.w;
        }
#pragma unroll
        for (int mask = 16; mask <= 32; mask <<= 1) {
            a0 += __shfl_xor(a0, mask, 64);
            a1 += __shfl_xor(a1, mask, 64);
            a2 += __shfl_xor(a2, mask, 64);
            a3 += __shfl_xor(a3, mask, 64);
        }
        if (e == 0) {
            float* orow = out + (size_t)o * C;
            if (first) {
                orow[j] = a0; orow[16 + j] = a1; orow[32 + j] = a2; orow[48 + j] = a3;
            } else {
                orow[j] += a0; orow[16 + j] += a1; orow[32 + j] += a2; orow[48 + j] += a3;
            }
        }
    }
}

// ===========================================================================
// Fallback conv (proven): atomic scatter-add. Used only if workspace is too
// small for the sorted-partial path.
// ===========================================================================
__global__ __launch_bounds__(256)
void conv_mfma(const __bf16* __restrict__ featb, const __bf16* __restrict__ wtb,
               const int* __restrict__ in_idx, const int* __restrict__ out_idx,
               float* __restrict__ out)
{
    constexpr int TP = 256;
    constexpr int STRIDE = 72;
    __shared__ __bf16 sA[TP * STRIDE];
    __shared__ int s_out[TP];

    const int k = blockIdx.y;
    const int tile_base = blockIdx.x * TP;
    const int t = threadIdx.x;
    const int lane = t & 63;
    const int wave = t >> 6;
    const int m16 = lane & 15;
    const int quad = lane >> 4;

    const __bf16* Wt = wtb + (size_t)k * C * C;
    bf16x8 bfrag[4][2];
#pragma unroll
    for (int nt = 0; nt < 4; ++nt)
#pragma unroll
        for (int kc = 0; kc < 2; ++kc)
            bfrag[nt][kc] = *(const bf16x8*)(Wt + (nt * 16 + m16) * C + kc * 32 + quad * 8);

    {
        const int pair = tile_base + t;
        s_out[t] = (pair < PPK) ? out_idx[(size_t)k * PPK + pair] : 0;
    }

    const int c8 = t & 7;
    const int r0 = t >> 3;
#pragma unroll
    for (int it = 0; it < 8; ++it) {
        const int r = r0 + it * 32;
        const int pair = tile_base + r;
        const int row = (pair < PPK) ? in_idx[(size_t)k * PPK + pair] : 0;
        const float4 v = *(const float4*)(featb + (size_t)row * C + c8 * 8);
        *(float4*)(sA + r * STRIDE + c8 * 8) = v;
    }
    __syncthreads();

    f32x4 acc[4][4] = {};
    const int mbase = wave * 64;
#pragma unroll
    for (int kc = 0; kc < 2; ++kc) {
        bf16x8 afrag[4];
#pragma unroll
        for (int mt = 0; mt < 4; ++mt)
            afrag[mt] = *(const bf16x8*)(sA + (mbase + mt * 16 + m16) * STRIDE + kc * 32 + quad * 8);
#pragma unroll
        for (int nt = 0; nt < 4; ++nt)
#pragma unroll
            for (int mt = 0; mt < 4; ++mt)
                acc[mt][nt] = __builtin_amdgcn_mfma_f32_16x16x32_bf16(
                    afrag[mt], bfrag[nt][kc], acc[mt][nt], 0, 0, 0);
    }

#pragma unroll
    for (int mt = 0; mt < 4; ++mt) {
#pragma unroll
        for (int reg = 0; reg < 4; ++reg) {
            const int r = mbase + mt * 16 + quad * 4 + reg;
            const int pair = tile_base + r;
            if (pair < PPK) {
                const int o = s_out[r];
                float* orow = out + (size_t)o * C + m16;
#pragma unroll
                for (int nt = 0; nt < 4; ++nt)
                    unsafeAtomicAdd(orow + nt * 16, acc[mt][nt][reg]);
            }
        }
    }
}

// ---------------------------------------------------------------------------
// Per-channel sum / sum-of-squares (bias skipped: cancels under BN).
// ---------------------------------------------------------------------------
__global__ __launch_bounds__(256)
void stats_kernel(const float* __restrict__ out,
                  float* __restrict__ stats,
                  int rows_per_block)
{
    __shared__ float ssum[256];
    __shared__ float ssq[256];
    const int c   = threadIdx.x & 63;
    const int sub = threadIdx.x >> 6;
    const int row0 = blockIdx.x * rows_per_block;
    const int row1 = min(row0 + rows_per_block, N_VOX);
    float s = 0.f, q = 0.f;
    for (int r = row0 + sub; r < row1; r += 4) {
        const float v = out[(size_t)r * C + c];
        s += v;
        q += v * v;
    }
    ssum[threadIdx.x] = s;
    ssq[threadIdx.x]  = q;
    __syncthreads();
    if (sub == 0) {
        s = ssum[c] + ssum[64 + c] + ssum[128 + c] + ssum[192 + c];
        q = ssq[c]  + ssq[64 + c]  + ssq[128 + c]  + ssq[192 + c];
        unsafeAtomicAdd(&stats[c], s);
        unsafeAtomicAdd(&stats[64 + c], q);
    }
}

__global__ void finalize_params(const float* __restrict__ stats,
                                const float* __restrict__ gamma,
                                const float* __restrict__ beta,
                                float* __restrict__ ss)
{
    const int c = threadIdx.x;
    const float inv_n = 1.0f / (float)N_VOX;
    const float mean  = stats[c] * inv_n;
    const float var   = stats[64 + c] * inv_n - mean * mean;
    const float scale = rsqrtf(var + BN_EPS) * gamma[c];
    ss[c]      = scale;
    ss[64 + c] = beta[c] - mean * scale;
}

__global__ __launch_bounds__(256)
void norm_kernel(float* __restrict__ out, const float* __restrict__ ss)
{
    const size_t total4 = (size_t)N_VOX * C / 4;
    const size_t idx = (size_t)blockIdx.x * blockDim.x + threadIdx.x;
    if (idx >= total4) return;
    const int c4 = (int)(idx & 15);
    float4 v = ((const float4*)out)[idx];
    const float4 sc = ((const float4*)ss)[c4];
    const float4 sh = ((const float4*)(ss + 64))[c4];
    v.x = fmaxf(v.x * sc.x + sh.x, 0.f);
    v.y = fmaxf(v.y * sc.y + sh.y, 0.f);
    v.z = fmaxf(v.z * sc.z + sh.z, 0.f);
    v.w = fmaxf(v.w * sc.w + sh.w, 0.f);
    ((float4*)out)[idx] = v;
}

static inline size_t align_up(size_t x) { return (x + 255) & ~(size_t)255; }

extern "C" void kernel_launch(void* const* d_in, const int* in_sizes, int n_in,
                              void* d_out, int out_size, void* d_ws, size_t ws_size,
                              hipStream_t stream)
{
    const float* features = (const float*)d_in[0];
    const float* weight   = (const float*)d_in[1];
    // d_in[2] = bias: cancels under BN, unused.
    const float* gamma    = (const float*)d_in[3];
    const float* beta     = (const float*)d_in[4];
    const int*   in_idx   = (const int*)d_in[5];
    const int*   out_idx  = (const int*)d_in[6];
    float* out = (float*)d_out;

    // workspace layout
    char* base = (char*)d_ws;
    size_t off = 0;
    __bf16* featb = (__bf16*)(base + off); off += align_up((size_t)N_VOX * C * 2);
    __bf16* wtb   = (__bf16*)(base + off); off += align_up((size_t)KOFF * C * C * 2);
    float*  stats = (float*)(base + off);  off += align_up(128 * 4);
    float*  ss    = (float*)(base + off);  off += align_up(128 * 4);
    unsigned* counts  = (unsigned*)(base + off); off += align_up((size_t)N_VOX * 4);
    unsigned* offsets = (unsigned*)(base + off); off += align_up((size_t)N_VOX * 4);
    unsigned* bsums   = (unsigned*)(base + off); off += align_up(256 * 4);
    const size_t fixed = off;

    // per k-offset per chunk: slot u32[PPK] + partial bf16[PPK][64] = 132 B/pair.
    // No L3 cap (round-3's 9-offset cap bought nothing): fewest chunks wins.
    int g_cap = 0;
    if (ws_size > fixed)
        g_cap = (int)((ws_size - fixed) / ((size_t)PPK * 132));
    if (g_cap > KOFF) g_cap = KOFF;

    hipMemsetAsync(stats, 0, 128 * sizeof(float), stream);

    const size_t total4 = (size_t)N_VOX * C / 4;
    convert_features<<<(int)((total4 + 255) / 256), 256, 0, stream>>>(features, featb);
    convert_weight<<<KOFF, 256, 0, stream>>>(weight, wtb);

    if (g_cap >= 2) {
        // sorted-partial path: invert rulebook per chunk, no f32 atomics.
        const int G = (KOFF + g_cap - 1) / g_cap;
        const int gmax = (KOFF + G - 1) / G;
        unsigned* slot = (unsigned*)(base + off);
        __bf16* partial = (__bf16*)(base + off + align_up((size_t)gmax * PPK * 4));
        const int gbase_sz = KOFF / G, rem = KOFF % G;
        // counts must be zero before the first hist; scan1 re-zeroes each chunk.
        hipMemsetAsync(counts, 0, (size_t)N_VOX * 4, stream);
        int k0 = 0;
        for (int ci = 0; ci < G; ++ci) {
            const int g = gbase_sz + (ci < rem ? 1 : 0);
            const int np = g * PPK;
            hist_kernel<<<(np + 255) / 256, 256, 0, stream>>>(out_idx, counts, slot, k0, np);
            scan1<<<(N_VOX + 1023) / 1024, 256, 0, stream>>>(counts, offsets, bsums);
            scan2<<<1, 256, 0, stream>>>(bsums, (N_VOX + 1023) / 1024);
            scan3<<<(N_VOX + 255) / 256, 256, 0, stream>>>(offsets, bsums);
            slot_fill<<<(np + 255) / 256, 256, 0, stream>>>(out_idx, offsets, slot, k0, np);
            dim3 cgrid((PPK + 255) / 256, g);
            conv_scatter<<<cgrid, 256, 0, stream>>>(featb, wtb, in_idx, slot, partial, k0);
            reduce_kernel<<<1024, 256, 0, stream>>>(partial, offsets, out,
                                                    ci == 0 ? 1 : 0, (unsigned)np);
            k0 += g;
        }
    } else {
        // fallback: proven atomic path
        hipMemsetAsync(out, 0, (size_t)N_VOX * C * sizeof(float), stream);
        dim3 cgrid((PPK + 255) / 256, KOFF);
        conv_mfma<<<cgrid, 256, 0, stream>>>(featb, wtb, in_idx, out_idx, out);
    }

    const int rpb = (N_VOX + 511) / 512;
    stats_kernel<<<512, 256, 0, stream>>>(out, stats, rpb);

    finalize_params<<<1, 64, 0, stream>>>(stats, gamma, beta, ss);

    norm_kernel<<<(int)((total4 + 255) / 256), 256, 0, stream>>>(out, ss);
}